// Round 16
// baseline (38.674 us; speedup 1.0000x reference)
//
#include <hip/hip_runtime.h>
#include <hip/hip_bf16.h>

#define BATCH 4096
#define DIM 256

typedef __attribute__((ext_vector_type(8))) short short8;
typedef __attribute__((ext_vector_type(4))) float f32x4;

__device__ inline unsigned short f2bf(float f) {
    union { float f; unsigned u; } x; x.f = f;
    unsigned r = x.u + 0x7fffu + ((x.u >> 16) & 1u);
    return (unsigned short)(r >> 16);
}

// ---------------- FAST PATH ----------------
// ws layout: zib bf16[4096*256] (2MB) | zjb bf16[4096*256] (2MB)
//            | pos f32[4096] | rowsum f32[4096] | colsum f32[4096]
//            | tmp f32 | counter i32
#define WS_FAST_BYTES ((size_t)4 * 1024 * 1024 + 3 * 4096 * sizeof(float) + 64)

// XOR-swizzled LDS addressing for a [128][64] bf16 tile (row stride 128 B).
// byte ^= (r&7)<<4; same involution on ds_write and ds_read (verified r6-r15:
// uniform 8-slot spread, zero excess bank conflict).
__device__ inline short8* lds8(unsigned short* base, int r, int c) {
    int byte = (r << 7) + (c << 1);
    byte ^= (r & 7) << 4;
    return reinterpret_cast<short8*>(reinterpret_cast<char*>(base) + byte);
}

// Kernel 1: normalize rows -> bf16 buffers, fp32 positives, zero accumulators.
__global__ __launch_bounds__(256) void norm2_kernel(
    const float* __restrict__ zi, const float* __restrict__ zj,
    unsigned short* __restrict__ zib, unsigned short* __restrict__ zjb,
    float* __restrict__ pos, float* __restrict__ rowsum, float* __restrict__ colsum,
    float* __restrict__ tmp, int* __restrict__ counter) {
    const int tid = threadIdx.x;
    if (blockIdx.x < 16) rowsum[blockIdx.x * 256 + tid] = 0.f;
    else if (blockIdx.x < 32) colsum[(blockIdx.x - 16) * 256 + tid] = 0.f;
    else if (blockIdx.x == 32 && tid == 0) { tmp[0] = 0.f; *counter = 0; }

    const int wid  = tid >> 6;
    const int lane = tid & 63;
    const int row  = blockIdx.x * 4 + wid;
    const float4 vi = reinterpret_cast<const float4*>(zi)[row * 64 + lane];
    const float4 vj = reinterpret_cast<const float4*>(zj)[row * 64 + lane];
    float si = vi.x * vi.x + vi.y * vi.y + vi.z * vi.z + vi.w * vi.w;
    float sj = vj.x * vj.x + vj.y * vj.y + vj.z * vj.z + vj.w * vj.w;
    float d  = vi.x * vj.x + vi.y * vj.y + vi.z * vj.z + vi.w * vj.w;
#pragma unroll
    for (int o = 1; o < 64; o <<= 1) {
        si += __shfl_xor(si, o);
        sj += __shfl_xor(sj, o);
        d  += __shfl_xor(d, o);
    }
    const float ii = 1.0f / fmaxf(sqrtf(si), 1e-12f);
    const float ij = 1.0f / fmaxf(sqrtf(sj), 1e-12f);
    ushort4 a = make_ushort4(f2bf(vi.x * ii), f2bf(vi.y * ii), f2bf(vi.z * ii), f2bf(vi.w * ii));
    ushort4 b = make_ushort4(f2bf(vj.x * ij), f2bf(vj.y * ij), f2bf(vj.z * ij), f2bf(vj.w * ij));
    reinterpret_cast<ushort4*>(zib)[row * 64 + lane] = a;
    reinterpret_cast<ushort4*>(zjb)[row * 64 + lane] = b;
    if (lane == 0) pos[row] = d * ii * ij;
}

// Kernel 2: round-15 proven structure (two 128x128 tiles/block, dbuf pipeline,
// XCD swizzle, setprio around MFMAs) + FUSED final loss: last-finishing block
// (ticket 511) computes sum[log(rowsum)+log(colsum)-4*pos]/(2B) -> out.
// Ticket pattern correctness-validated in round 5 (passed absmax 0.0).
__global__ __launch_bounds__(256) void sim2_kernel(
    const unsigned short* __restrict__ zib, const unsigned short* __restrict__ zjb,
    float* __restrict__ rowsum, float* __restrict__ colsum,
    const float* __restrict__ pos, int* __restrict__ counter,
    float* __restrict__ out) {
    __shared__ unsigned short As[2][128 * 64];
    __shared__ unsigned short Bs[2][128 * 64];
    const int b    = blockIdx.x;            // 0..511
    const int tid  = threadIdx.x;
    const int wave = tid >> 6;
    const int lane = tid & 63;
    const int wr = (wave >> 1) << 6;        // 0 or 64
    const int wc = (wave & 1) << 6;         // 0 or 64
    const int fr = lane & 15;
    const int ko = (lane >> 4) << 3;        // k offset 0,8,16,24

    const int bi  = ((b & 7) << 2) + ((b >> 3) & 3);   // same for both tiles
    const int bj0 = b >> 5;                            // 0..15
    const int bj1 = bj0 + 16;                          // tile b+512
    const unsigned short* gA  = zib + (size_t)bi  * 128 * DIM;
    const unsigned short* gB0 = zjb + (size_t)bj0 * 128 * DIM;
    const unsigned short* gB1 = zjb + (size_t)bj1 * 128 * DIM;

    int rr[4], cc[4];
#pragma unroll
    for (int i = 0; i < 4; ++i) {
        int chunk = i * 256 + tid;
        rr[i] = chunk >> 3;
        cc[i] = (chunk & 7) << 3;
    }
    const float SC = 2.0f * 1.44269504088896f;   // exp(2x) = exp2(x*SC)

    // Epilogue: C/D layout (HW-verified r3-r15): S[rb+(lane>>4)*4+r][cb+(lane&15)].
    auto epilogue = [&](f32x4 (&acc)[4][4], int bjx) {
        float rs[4][4];
#pragma unroll
        for (int m = 0; m < 4; ++m)
#pragma unroll
            for (int r = 0; r < 4; ++r) rs[m][r] = 0.f;
        float csn[4] = {0.f, 0.f, 0.f, 0.f};
#pragma unroll
        for (int m = 0; m < 4; ++m)
#pragma unroll
            for (int n = 0; n < 4; ++n)
#pragma unroll
                for (int r = 0; r < 4; ++r) {
                    float e = exp2f(acc[m][n][r] * SC);
                    rs[m][r] += e;
                    csn[n] += e;
                }
#pragma unroll
        for (int m = 0; m < 4; ++m)
#pragma unroll
            for (int r = 0; r < 4; ++r) {
                float v = rs[m][r];
                v += __shfl_xor(v, 1); v += __shfl_xor(v, 2);
                v += __shfl_xor(v, 4); v += __shfl_xor(v, 8);
                if ((lane & 15) == 0) {
                    int row = bi * 128 + wr + m * 16 + (lane >> 4) * 4 + r;
                    atomicAdd(&rowsum[row], v);
                }
            }
#pragma unroll
        for (int n = 0; n < 4; ++n) {
            float v = csn[n];
            v += __shfl_xor(v, 16); v += __shfl_xor(v, 32);
            if (lane < 16) atomicAdd(&colsum[bjx * 128 + wc + n * 16 + lane], v);
        }
    };

    short8 pa[4], pb[4];
#pragma unroll
    for (int i = 0; i < 4; ++i) {           // prologue: tile0 phase0
        pa[i] = *reinterpret_cast<const short8*>(gA  + rr[i] * DIM + cc[i]);
        pb[i] = *reinterpret_cast<const short8*>(gB0 + rr[i] * DIM + cc[i]);
    }
#pragma unroll
    for (int i = 0; i < 4; ++i) {
        *lds8(As[0], rr[i], cc[i]) = pa[i];
        *lds8(Bs[0], rr[i], cc[i]) = pb[i];
    }

    f32x4 acc[4][4] = {};

#pragma unroll
    for (int p = 0; p < 8; ++p) {           // 2 tiles x 4 K-phases, one pipeline
        const int cur = p & 1;
        __syncthreads();                    // buf[cur] visible to all waves
        if (p < 7) {                        // prefetch phase p+1 (may cross tile)
            const int np = p + 1;
            const int co = (np & 3) * 64;
            const unsigned short* gBn = (np >> 2) ? gB1 : gB0;
#pragma unroll
            for (int i = 0; i < 4; ++i) {
                pa[i] = *reinterpret_cast<const short8*>(gA  + rr[i] * DIM + co + cc[i]);
                pb[i] = *reinterpret_cast<const short8*>(gBn + rr[i] * DIM + co + cc[i]);
            }
        }
        __builtin_amdgcn_s_setprio(1);      // T5: favor MFMA-phase wave on CU
#pragma unroll
        for (int kk = 0; kk < 2; ++kk) {
            int c = kk * 32 + ko;
            short8 a0 = *lds8(As[cur], wr +      fr, c);
            short8 a1 = *lds8(As[cur], wr + 16 + fr, c);
            short8 a2 = *lds8(As[cur], wr + 32 + fr, c);
            short8 a3 = *lds8(As[cur], wr + 48 + fr, c);
            short8 b0 = *lds8(Bs[cur], wc +      fr, c);
            short8 b1 = *lds8(Bs[cur], wc + 16 + fr, c);
            short8 b2 = *lds8(Bs[cur], wc + 32 + fr, c);
            short8 b3 = *lds8(Bs[cur], wc + 48 + fr, c);
            acc[0][0] = __builtin_amdgcn_mfma_f32_16x16x32_bf16(a0, b0, acc[0][0], 0, 0, 0);
            acc[0][1] = __builtin_amdgcn_mfma_f32_16x16x32_bf16(a0, b1, acc[0][1], 0, 0, 0);
            acc[0][2] = __builtin_amdgcn_mfma_f32_16x16x32_bf16(a0, b2, acc[0][2], 0, 0, 0);
            acc[0][3] = __builtin_amdgcn_mfma_f32_16x16x32_bf16(a0, b3, acc[0][3], 0, 0, 0);
            acc[1][0] = __builtin_amdgcn_mfma_f32_16x16x32_bf16(a1, b0, acc[1][0], 0, 0, 0);
            acc[1][1] = __builtin_amdgcn_mfma_f32_16x16x32_bf16(a1, b1, acc[1][1], 0, 0, 0);
            acc[1][2] = __builtin_amdgcn_mfma_f32_16x16x32_bf16(a1, b2, acc[1][2], 0, 0, 0);
            acc[1][3] = __builtin_amdgcn_mfma_f32_16x16x32_bf16(a1, b3, acc[1][3], 0, 0, 0);
            acc[2][0] = __builtin_amdgcn_mfma_f32_16x16x32_bf16(a2, b0, acc[2][0], 0, 0, 0);
            acc[2][1] = __builtin_amdgcn_mfma_f32_16x16x32_bf16(a2, b1, acc[2][1], 0, 0, 0);
            acc[2][2] = __builtin_amdgcn_mfma_f32_16x16x32_bf16(a2, b2, acc[2][2], 0, 0, 0);
            acc[2][3] = __builtin_amdgcn_mfma_f32_16x16x32_bf16(a2, b3, acc[2][3], 0, 0, 0);
            acc[3][0] = __builtin_amdgcn_mfma_f32_16x16x32_bf16(a3, b0, acc[3][0], 0, 0, 0);
            acc[3][1] = __builtin_amdgcn_mfma_f32_16x16x32_bf16(a3, b1, acc[3][1], 0, 0, 0);
            acc[3][2] = __builtin_amdgcn_mfma_f32_16x16x32_bf16(a3, b2, acc[3][2], 0, 0, 0);
            acc[3][3] = __builtin_amdgcn_mfma_f32_16x16x32_bf16(a3, b3, acc[3][3], 0, 0, 0);
        }
        __builtin_amdgcn_s_setprio(0);
        if (p == 3) {                       // tile0 done: epilogue hides the
            epilogue(acc, bj0);             // tile1-phase0 loads in flight
#pragma unroll
            for (int m = 0; m < 4; ++m)
#pragma unroll
                for (int n = 0; n < 4; ++n) acc[m][n] = f32x4{0.f, 0.f, 0.f, 0.f};
        }
        if (p < 7) {                        // write prefetched phase to buf^1
#pragma unroll
            for (int i = 0; i < 4; ++i) {
                *lds8(As[cur ^ 1], rr[i], cc[i]) = pa[i];
                *lds8(Bs[cur ^ 1], rr[i], cc[i]) = pb[i];
            }
        }
    }
    epilogue(acc, bj1);                     // tile1 epilogue

    // ---- Fused final loss (ticket; r5-validated pattern) ----
    __syncthreads();                        // drains all this block's atomics
                                            // (compiler emits vmcnt(0) before barrier)
    int* tick = (int*)As;                   // reuse LDS
    if (tid == 0) {
        __threadfence();                    // release
        tick[0] = atomicAdd(counter, 1);
    }
    __syncthreads();
    if (tick[0] == 511) {                   // last block: all sums complete
        __threadfence();                    // acquire (invalidate stale L1)
        const float4* r4 = reinterpret_cast<const float4*>(rowsum);
        const float4* c4 = reinterpret_cast<const float4*>(colsum);
        const float4* p4 = reinterpret_cast<const float4*>(pos);
        float a = 0.f;
#pragma unroll
        for (int q = 0; q < 4; ++q) {       // 1024 float4 per array, coalesced
            float4 r = r4[q * 256 + tid];
            float4 c = c4[q * 256 + tid];
            float4 p = p4[q * 256 + tid];
            a += __logf(r.x) + __logf(r.y) + __logf(r.z) + __logf(r.w);
            a += __logf(c.x) + __logf(c.y) + __logf(c.z) + __logf(c.w);
            a -= 4.0f * (p.x + p.y + p.z + p.w);
        }
#pragma unroll
        for (int o = 1; o < 64; o <<= 1) a += __shfl_xor(a, o);
        float* red = (float*)Bs;            // reuse LDS
        if ((tid & 63) == 0) red[tid >> 6] = a;
        __syncthreads();
        if (tid == 0)
            out[0] = (red[0] + red[1] + red[2] + red[3]) * (1.0f / (2.0f * BATCH));
    }
}

// ---------------- FALLBACK PATH (round-3 verified, needs only 80 KB ws) ----------------
__device__ inline short8* ldsp128(unsigned short* base, int r, int c) {
    int byte = (r << 8) + (c << 1);
    byte ^= (r & 7) << 4;
    return reinterpret_cast<short8*>(reinterpret_cast<char*>(base) + byte);
}

__global__ __launch_bounds__(256) void init_kernel(float* __restrict__ rowsum,
                                                   float* __restrict__ colsum) {
    int i = blockIdx.x * 256 + threadIdx.x;
    rowsum[i] = 0.f;
    colsum[i] = 0.f;
}

__global__ __launch_bounds__(256) void norm_kernel(
    const float* __restrict__ zi, const float* __restrict__ zj,
    float* __restrict__ ninv_i, float* __restrict__ ninv_j, float* __restrict__ pos) {
    const int wid  = threadIdx.x >> 6;
    const int lane = threadIdx.x & 63;
    const int row  = blockIdx.x * 4 + wid;
    const float4 vi = reinterpret_cast<const float4*>(zi)[row * 64 + lane];
    const float4 vj = reinterpret_cast<const float4*>(zj)[row * 64 + lane];
    float si = vi.x * vi.x + vi.y * vi.y + vi.z * vi.z + vi.w * vi.w;
    float sj = vj.x * vj.x + vj.y * vj.y + vj.z * vj.z + vj.w * vj.w;
    float d  = vi.x * vj.x + vi.y * vj.y + vi.z * vj.z + vi.w * vj.w;
#pragma unroll
    for (int o = 1; o < 64; o <<= 1) {
        si += __shfl_xor(si, o);
        sj += __shfl_xor(sj, o);
        d  += __shfl_xor(d, o);
    }
    if (lane == 0) {
        float ii = 1.0f / fmaxf(sqrtf(si), 1e-12f);
        float ij = 1.0f / fmaxf(sqrtf(sj), 1e-12f);
        ninv_i[row] = ii;
        ninv_j[row] = ij;
        pos[row] = d * ii * ij;
    }
}

__global__ __launch_bounds__(256) void sim_kernel(
    const float* __restrict__ zi, const float* __restrict__ zj,
    const float* __restrict__ ninv_i, const float* __restrict__ ninv_j,
    float* __restrict__ rowsum, float* __restrict__ colsum) {
    __shared__ unsigned short As[64 * 128];
    __shared__ unsigned short Bs[64 * 128];
    const int bi = blockIdx.x, bj = blockIdx.y;
    const int tid  = threadIdx.x;
    const int wave = tid >> 6;
    const int lane = tid & 63;
    const int wr = (wave >> 1) << 5;
    const int wc = (wave & 1) << 5;
    const int fr = lane & 15;
    const int ko = (lane >> 4) << 3;

    f32x4 acc[2][2] = {};

    for (int h = 0; h < 2; ++h) {
#pragma unroll
        for (int it = 0; it < 4; ++it) {
            int chunk = tid + it * 256;
            int r = chunk >> 4;
            int c = (chunk & 15) << 3;
            int ga = bi * 64 + r;
            int gb = bj * 64 + r;
            int cgl = h * 128 + c;
            const float4* pa = reinterpret_cast<const float4*>(zi) + ga * 64 + (cgl >> 2);
            const float4* pb = reinterpret_cast<const float4*>(zj) + gb * 64 + (cgl >> 2);
            float4 a0 = pa[0], a1 = pa[1];
            float4 b0 = pb[0], b1 = pb[1];
            float ia = ninv_i[ga];
            float ib = ninv_j[gb];
            short8 va, vb;
            va[0] = (short)f2bf(a0.x * ia); va[1] = (short)f2bf(a0.y * ia);
            va[2] = (short)f2bf(a0.z * ia); va[3] = (short)f2bf(a0.w * ia);
            va[4] = (short)f2bf(a1.x * ia); va[5] = (short)f2bf(a1.y * ia);
            va[6] = (short)f2bf(a1.z * ia); va[7] = (short)f2bf(a1.w * ia);
            vb[0] = (short)f2bf(b0.x * ib); vb[1] = (short)f2bf(b0.y * ib);
            vb[2] = (short)f2bf(b0.z * ib); vb[3] = (short)f2bf(b0.w * ib);
            vb[4] = (short)f2bf(b1.x * ib); vb[5] = (short)f2bf(b1.y * ib);
            vb[6] = (short)f2bf(b1.z * ib); vb[7] = (short)f2bf(b1.w * ib);
            *ldsp128(As, r, c) = va;
            *ldsp128(Bs, r, c) = vb;
        }
        __syncthreads();
#pragma unroll
        for (int kk = 0; kk < 4; ++kk) {
            int c = kk * 32 + ko;
            short8 a0 = *ldsp128(As, wr + fr, c);
            short8 a1 = *ldsp128(As, wr + 16 + fr, c);
            short8 b0 = *ldsp128(Bs, wc + fr, c);
            short8 b1 = *ldsp128(Bs, wc + 16 + fr, c);
            acc[0][0] = __builtin_amdgcn_mfma_f32_16x16x32_bf16(a0, b0, acc[0][0], 0, 0, 0);
            acc[0][1] = __builtin_amdgcn_mfma_f32_16x16x32_bf16(a0, b1, acc[0][1], 0, 0, 0);
            acc[1][0] = __builtin_amdgcn_mfma_f32_16x16x32_bf16(a1, b0, acc[1][0], 0, 0, 0);
            acc[1][1] = __builtin_amdgcn_mfma_f32_16x16x32_bf16(a1, b1, acc[1][1], 0, 0, 0);
        }
        __syncthreads();
    }

    const float SC = 2.0f * 1.44269504088896f;
    float rs[2][4];
#pragma unroll
    for (int m = 0; m < 2; ++m)
#pragma unroll
        for (int r = 0; r < 4; ++r) rs[m][r] = 0.f;
    float cs[2] = {0.f, 0.f};
#pragma unroll
    for (int m = 0; m < 2; ++m)
#pragma unroll
        for (int n = 0; n < 2; ++n)
#pragma unroll
            for (int r = 0; r < 4; ++r) {
                float e = exp2f(acc[m][n][r] * SC);
                rs[m][r] += e;
                cs[n] += e;
            }
#pragma unroll
    for (int m = 0; m < 2; ++m)
#pragma unroll
        for (int r = 0; r < 4; ++r) {
            float v = rs[m][r];
            v += __shfl_xor(v, 1); v += __shfl_xor(v, 2);
            v += __shfl_xor(v, 4); v += __shfl_xor(v, 8);
            if ((lane & 15) == 0) {
                int row = bi * 64 + wr + m * 16 + (lane >> 4) * 4 + r;
                atomicAdd(&rowsum[row], v);
            }
        }
#pragma unroll
    for (int n = 0; n < 2; ++n) {
        float v = cs[n];
        v += __shfl_xor(v, 16); v += __shfl_xor(v, 32);
        if (lane < 16) atomicAdd(&colsum[bj * 64 + wc + n * 16 + lane], v);
    }
}

__global__ __launch_bounds__(256) void loss_kernel(
    const float* __restrict__ rowsum, const float* __restrict__ colsum,
    const float* __restrict__ pos, float* __restrict__ out) {
    float a = 0.f;
    for (int i = threadIdx.x; i < BATCH; i += 256)
        a += __logf(rowsum[i]) + __logf(colsum[i]) - 4.0f * pos[i];
#pragma unroll
    for (int o = 1; o < 64; o <<= 1) a += __shfl_xor(a, o);
    __shared__ float red[4];
    if ((threadIdx.x & 63) == 0) red[threadIdx.x >> 6] = a;
    __syncthreads();
    if (threadIdx.x == 0) {
        float t = red[0] + red[1] + red[2] + red[3];
        out[0] = t * (1.0f / (2.0f * BATCH));
    }
}

extern "C" void kernel_launch(void* const* d_in, const int* in_sizes, int n_in,
                              void* d_out, int out_size, void* d_ws, size_t ws_size,
                              hipStream_t stream) {
    const float* zi = (const float*)d_in[0];
    const float* zj = (const float*)d_in[1];
    char* ws = (char*)d_ws;

    if (ws_size >= WS_FAST_BYTES) {
        unsigned short* zib = (unsigned short*)ws;
        unsigned short* zjb = (unsigned short*)(ws + (size_t)2 * 1024 * 1024);
        float* pos    = (float*)(ws + (size_t)4 * 1024 * 1024);
        float* rowsum = pos + 4096;
        float* colsum = rowsum + 4096;
        float* tmp    = colsum + 4096;
        int*   counter = (int*)(tmp + 1);
        norm2_kernel<<<BATCH / 4, 256, 0, stream>>>(zi, zj, zib, zjb, pos, rowsum, colsum, tmp, counter);
        sim2_kernel<<<512, 256, 0, stream>>>(zib, zjb, rowsum, colsum, pos, counter, (float*)d_out);
    } else {
        float* wsf = (float*)ws;
        float* ninv_i = wsf;
        float* ninv_j = wsf + 4096;
        float* pos    = wsf + 8192;
        float* rowsum = wsf + 12288;
        float* colsum = wsf + 16384;
        init_kernel<<<16, 256, 0, stream>>>(rowsum, colsum);
        norm_kernel<<<BATCH / 4, 256, 0, stream>>>(zi, zj, ninv_i, ninv_j, pos);
        dim3 grid(64, 64);
        sim_kernel<<<grid, 256, 0, stream>>>(zi, zj, ninv_i, ninv_j, rowsum, colsum);
        loss_kernel<<<1, 256, 0, stream>>>(rowsum, colsum, pos, (float*)d_out);
    }
}

// Round 17
// 31.460 us; speedup vs baseline: 1.2293x; 1.2293x over previous
//
#include <hip/hip_runtime.h>
#include <hip/hip_bf16.h>

#define BATCH 4096
#define DIM 256

typedef __attribute__((ext_vector_type(8))) short short8;
typedef __attribute__((ext_vector_type(4))) float f32x4;

__device__ inline unsigned short f2bf(float f) {
    union { float f; unsigned u; } x; x.f = f;
    unsigned r = x.u + 0x7fffu + ((x.u >> 16) & 1u);
    return (unsigned short)(r >> 16);
}

// ---------------- FAST PATH ----------------
// ws layout: zib bf16[4096*256] (2MB) | zjb bf16[4096*256] (2MB)
//            | pos f32[4096] | rowsum f32[4096] | colsum f32[4096]
//            | tmp f32 | counter i32
#define WS_FAST_BYTES ((size_t)4 * 1024 * 1024 + 3 * 4096 * sizeof(float) + 64)

// XOR-swizzled LDS addressing for a [128][64] bf16 tile (row stride 128 B).
// byte ^= (r&7)<<4; same involution on ds_write and ds_read (verified r6-r15:
// uniform 8-slot spread, zero excess bank conflict).
__device__ inline short8* lds8(unsigned short* base, int r, int c) {
    int byte = (r << 7) + (c << 1);
    byte ^= (r & 7) << 4;
    return reinterpret_cast<short8*>(reinterpret_cast<char*>(base) + byte);
}

// Kernel 1: normalize rows -> bf16 buffers, fp32 positives, zero accumulators.
__global__ __launch_bounds__(256) void norm2_kernel(
    const float* __restrict__ zi, const float* __restrict__ zj,
    unsigned short* __restrict__ zib, unsigned short* __restrict__ zjb,
    float* __restrict__ pos, float* __restrict__ rowsum, float* __restrict__ colsum,
    float* __restrict__ tmp, int* __restrict__ counter) {
    const int tid = threadIdx.x;
    if (blockIdx.x < 16) rowsum[blockIdx.x * 256 + tid] = 0.f;
    else if (blockIdx.x < 32) colsum[(blockIdx.x - 16) * 256 + tid] = 0.f;
    else if (blockIdx.x == 32 && tid == 0) { tmp[0] = 0.f; *counter = 0; }

    const int wid  = tid >> 6;
    const int lane = tid & 63;
    const int row  = blockIdx.x * 4 + wid;
    const float4 vi = reinterpret_cast<const float4*>(zi)[row * 64 + lane];
    const float4 vj = reinterpret_cast<const float4*>(zj)[row * 64 + lane];
    float si = vi.x * vi.x + vi.y * vi.y + vi.z * vi.z + vi.w * vi.w;
    float sj = vj.x * vj.x + vj.y * vj.y + vj.z * vj.z + vj.w * vj.w;
    float d  = vi.x * vj.x + vi.y * vj.y + vi.z * vj.z + vi.w * vj.w;
#pragma unroll
    for (int o = 1; o < 64; o <<= 1) {
        si += __shfl_xor(si, o);
        sj += __shfl_xor(sj, o);
        d  += __shfl_xor(d, o);
    }
    const float ii = 1.0f / fmaxf(sqrtf(si), 1e-12f);
    const float ij = 1.0f / fmaxf(sqrtf(sj), 1e-12f);
    ushort4 a = make_ushort4(f2bf(vi.x * ii), f2bf(vi.y * ii), f2bf(vi.z * ii), f2bf(vi.w * ii));
    ushort4 b = make_ushort4(f2bf(vj.x * ij), f2bf(vj.y * ij), f2bf(vj.z * ij), f2bf(vj.w * ij));
    reinterpret_cast<ushort4*>(zib)[row * 64 + lane] = a;
    reinterpret_cast<ushort4*>(zjb)[row * 64 + lane] = b;
    if (lane == 0) pos[row] = d * ii * ij;
}

// Kernel 2: TWO 128x128 tiles per block in ONE continuous dbuf pipeline
// (round-13 structure) + T5 s_setprio around the MFMA cluster (round-15).
// Tiles b and b+512 share bi (XCD-chunked swizzle) -> A staged once.
__global__ __launch_bounds__(256) void sim2_kernel(
    const unsigned short* __restrict__ zib, const unsigned short* __restrict__ zjb,
    float* __restrict__ rowsum, float* __restrict__ colsum) {
    __shared__ unsigned short As[2][128 * 64];
    __shared__ unsigned short Bs[2][128 * 64];
    const int b    = blockIdx.x;            // 0..511
    const int tid  = threadIdx.x;
    const int wave = tid >> 6;
    const int lane = tid & 63;
    const int wr = (wave >> 1) << 6;        // 0 or 64
    const int wc = (wave & 1) << 6;         // 0 or 64
    const int fr = lane & 15;
    const int ko = (lane >> 4) << 3;        // k offset 0,8,16,24

    const int bi  = ((b & 7) << 2) + ((b >> 3) & 3);   // same for both tiles
    const int bj0 = b >> 5;                            // 0..15
    const int bj1 = bj0 + 16;                          // tile b+512
    const unsigned short* gA  = zib + (size_t)bi  * 128 * DIM;
    const unsigned short* gB0 = zjb + (size_t)bj0 * 128 * DIM;
    const unsigned short* gB1 = zjb + (size_t)bj1 * 128 * DIM;

    int rr[4], cc[4];
#pragma unroll
    for (int i = 0; i < 4; ++i) {
        int chunk = i * 256 + tid;
        rr[i] = chunk >> 3;
        cc[i] = (chunk & 7) << 3;
    }
    const float SC = 2.0f * 1.44269504088896f;   // exp(2x) = exp2(x*SC)

    // Epilogue: C/D layout (HW-verified r3-r15): S[rb+(lane>>4)*4+r][cb+(lane&15)].
    auto epilogue = [&](f32x4 (&acc)[4][4], int bjx) {
        float rs[4][4];
#pragma unroll
        for (int m = 0; m < 4; ++m)
#pragma unroll
            for (int r = 0; r < 4; ++r) rs[m][r] = 0.f;
        float csn[4] = {0.f, 0.f, 0.f, 0.f};
#pragma unroll
        for (int m = 0; m < 4; ++m)
#pragma unroll
            for (int n = 0; n < 4; ++n)
#pragma unroll
                for (int r = 0; r < 4; ++r) {
                    float e = exp2f(acc[m][n][r] * SC);
                    rs[m][r] += e;
                    csn[n] += e;
                }
#pragma unroll
        for (int m = 0; m < 4; ++m)
#pragma unroll
            for (int r = 0; r < 4; ++r) {
                float v = rs[m][r];
                v += __shfl_xor(v, 1); v += __shfl_xor(v, 2);
                v += __shfl_xor(v, 4); v += __shfl_xor(v, 8);
                if ((lane & 15) == 0) {
                    int row = bi * 128 + wr + m * 16 + (lane >> 4) * 4 + r;
                    atomicAdd(&rowsum[row], v);
                }
            }
#pragma unroll
        for (int n = 0; n < 4; ++n) {
            float v = csn[n];
            v += __shfl_xor(v, 16); v += __shfl_xor(v, 32);
            if (lane < 16) atomicAdd(&colsum[bjx * 128 + wc + n * 16 + lane], v);
        }
    };

    short8 pa[4], pb[4];
#pragma unroll
    for (int i = 0; i < 4; ++i) {           // prologue: tile0 phase0
        pa[i] = *reinterpret_cast<const short8*>(gA  + rr[i] * DIM + cc[i]);
        pb[i] = *reinterpret_cast<const short8*>(gB0 + rr[i] * DIM + cc[i]);
    }
#pragma unroll
    for (int i = 0; i < 4; ++i) {
        *lds8(As[0], rr[i], cc[i]) = pa[i];
        *lds8(Bs[0], rr[i], cc[i]) = pb[i];
    }

    f32x4 acc[4][4] = {};

#pragma unroll
    for (int p = 0; p < 8; ++p) {           // 2 tiles x 4 K-phases, one pipeline
        const int cur = p & 1;
        __syncthreads();                    // buf[cur] visible to all waves
        if (p < 7) {                        // prefetch phase p+1 (may cross tile)
            const int np = p + 1;
            const int co = (np & 3) * 64;
            const unsigned short* gBn = (np >> 2) ? gB1 : gB0;
#pragma unroll
            for (int i = 0; i < 4; ++i) {
                pa[i] = *reinterpret_cast<const short8*>(gA  + rr[i] * DIM + co + cc[i]);
                pb[i] = *reinterpret_cast<const short8*>(gBn + rr[i] * DIM + co + cc[i]);
            }
        }
        __builtin_amdgcn_s_setprio(1);      // T5: favor MFMA-phase wave on CU
#pragma unroll
        for (int kk = 0; kk < 2; ++kk) {
            int c = kk * 32 + ko;
            short8 a0 = *lds8(As[cur], wr +      fr, c);
            short8 a1 = *lds8(As[cur], wr + 16 + fr, c);
            short8 a2 = *lds8(As[cur], wr + 32 + fr, c);
            short8 a3 = *lds8(As[cur], wr + 48 + fr, c);
            short8 b0 = *lds8(Bs[cur], wc +      fr, c);
            short8 b1 = *lds8(Bs[cur], wc + 16 + fr, c);
            short8 b2 = *lds8(Bs[cur], wc + 32 + fr, c);
            short8 b3 = *lds8(Bs[cur], wc + 48 + fr, c);
            acc[0][0] = __builtin_amdgcn_mfma_f32_16x16x32_bf16(a0, b0, acc[0][0], 0, 0, 0);
            acc[0][1] = __builtin_amdgcn_mfma_f32_16x16x32_bf16(a0, b1, acc[0][1], 0, 0, 0);
            acc[0][2] = __builtin_amdgcn_mfma_f32_16x16x32_bf16(a0, b2, acc[0][2], 0, 0, 0);
            acc[0][3] = __builtin_amdgcn_mfma_f32_16x16x32_bf16(a0, b3, acc[0][3], 0, 0, 0);
            acc[1][0] = __builtin_amdgcn_mfma_f32_16x16x32_bf16(a1, b0, acc[1][0], 0, 0, 0);
            acc[1][1] = __builtin_amdgcn_mfma_f32_16x16x32_bf16(a1, b1, acc[1][1], 0, 0, 0);
            acc[1][2] = __builtin_amdgcn_mfma_f32_16x16x32_bf16(a1, b2, acc[1][2], 0, 0, 0);
            acc[1][3] = __builtin_amdgcn_mfma_f32_16x16x32_bf16(a1, b3, acc[1][3], 0, 0, 0);
            acc[2][0] = __builtin_amdgcn_mfma_f32_16x16x32_bf16(a2, b0, acc[2][0], 0, 0, 0);
            acc[2][1] = __builtin_amdgcn_mfma_f32_16x16x32_bf16(a2, b1, acc[2][1], 0, 0, 0);
            acc[2][2] = __builtin_amdgcn_mfma_f32_16x16x32_bf16(a2, b2, acc[2][2], 0, 0, 0);
            acc[2][3] = __builtin_amdgcn_mfma_f32_16x16x32_bf16(a2, b3, acc[2][3], 0, 0, 0);
            acc[3][0] = __builtin_amdgcn_mfma_f32_16x16x32_bf16(a3, b0, acc[3][0], 0, 0, 0);
            acc[3][1] = __builtin_amdgcn_mfma_f32_16x16x32_bf16(a3, b1, acc[3][1], 0, 0, 0);
            acc[3][2] = __builtin_amdgcn_mfma_f32_16x16x32_bf16(a3, b2, acc[3][2], 0, 0, 0);
            acc[3][3] = __builtin_amdgcn_mfma_f32_16x16x32_bf16(a3, b3, acc[3][3], 0, 0, 0);
        }
        __builtin_amdgcn_s_setprio(0);
        if (p == 3) {                       // tile0 done: epilogue hides the
            epilogue(acc, bj0);             // tile1-phase0 loads in flight
#pragma unroll
            for (int m = 0; m < 4; ++m)
#pragma unroll
                for (int n = 0; n < 4; ++n) acc[m][n] = f32x4{0.f, 0.f, 0.f, 0.f};
        }
        if (p < 7) {                        // write prefetched phase to buf^1
#pragma unroll
            for (int i = 0; i < 4; ++i) {
                *lds8(As[cur ^ 1], rr[i], cc[i]) = pa[i];
                *lds8(Bs[cur ^ 1], rr[i], cc[i]) = pb[i];
            }
        }
    }
    epilogue(acc, bj1);                     // tile1 epilogue
}

// Kernel 3: parallel loss. 32 blocks x 256 threads, one element each.
__global__ __launch_bounds__(256) void loss2_kernel(
    const float* __restrict__ rowsum, const float* __restrict__ colsum,
    const float* __restrict__ pos, float* __restrict__ tmp,
    int* __restrict__ counter, float* __restrict__ out) {
    const int b = blockIdx.x;
    const int tid = threadIdx.x;
    const int idx = (b & 15) * 256 + tid;
    float a = (b < 16) ? (__logf(rowsum[idx]) - 4.0f * pos[idx])
                       : __logf(colsum[idx]);
#pragma unroll
    for (int o = 1; o < 64; o <<= 1) a += __shfl_xor(a, o);
    __shared__ float red[4];
    if ((tid & 63) == 0) red[tid >> 6] = a;
    __syncthreads();
    if (tid == 0) {
        float p = red[0] + red[1] + red[2] + red[3];
        atomicAdd(tmp, p);
        __threadfence();
        int t = atomicAdd(counter, 1);
        if (t == 31) {
            float tot = atomicAdd(tmp, 0.0f);   // coherent read of final total
            out[0] = tot * (1.0f / (2.0f * BATCH));
        }
    }
}

// ---------------- FALLBACK PATH (round-3 verified, needs only 80 KB ws) ----------------
__device__ inline short8* ldsp128(unsigned short* base, int r, int c) {
    int byte = (r << 8) + (c << 1);
    byte ^= (r & 7) << 4;
    return reinterpret_cast<short8*>(reinterpret_cast<char*>(base) + byte);
}

__global__ __launch_bounds__(256) void init_kernel(float* __restrict__ rowsum,
                                                   float* __restrict__ colsum) {
    int i = blockIdx.x * 256 + threadIdx.x;
    rowsum[i] = 0.f;
    colsum[i] = 0.f;
}

__global__ __launch_bounds__(256) void norm_kernel(
    const float* __restrict__ zi, const float* __restrict__ zj,
    float* __restrict__ ninv_i, float* __restrict__ ninv_j, float* __restrict__ pos) {
    const int wid  = threadIdx.x >> 6;
    const int lane = threadIdx.x & 63;
    const int row  = blockIdx.x * 4 + wid;
    const float4 vi = reinterpret_cast<const float4*>(zi)[row * 64 + lane];
    const float4 vj = reinterpret_cast<const float4*>(zj)[row * 64 + lane];
    float si = vi.x * vi.x + vi.y * vi.y + vi.z * vi.z + vi.w * vi.w;
    float sj = vj.x * vj.x + vj.y * vj.y + vj.z * vj.z + vj.w * vj.w;
    float d  = vi.x * vj.x + vi.y * vj.y + vi.z * vj.z + vi.w * vj.w;
#pragma unroll
    for (int o = 1; o < 64; o <<= 1) {
        si += __shfl_xor(si, o);
        sj += __shfl_xor(sj, o);
        d  += __shfl_xor(d, o);
    }
    if (lane == 0) {
        float ii = 1.0f / fmaxf(sqrtf(si), 1e-12f);
        float ij = 1.0f / fmaxf(sqrtf(sj), 1e-12f);
        ninv_i[row] = ii;
        ninv_j[row] = ij;
        pos[row] = d * ii * ij;
    }
}

__global__ __launch_bounds__(256) void sim_kernel(
    const float* __restrict__ zi, const float* __restrict__ zj,
    const float* __restrict__ ninv_i, const float* __restrict__ ninv_j,
    float* __restrict__ rowsum, float* __restrict__ colsum) {
    __shared__ unsigned short As[64 * 128];
    __shared__ unsigned short Bs[64 * 128];
    const int bi = blockIdx.x, bj = blockIdx.y;
    const int tid  = threadIdx.x;
    const int wave = tid >> 6;
    const int lane = tid & 63;
    const int wr = (wave >> 1) << 5;
    const int wc = (wave & 1) << 5;
    const int fr = lane & 15;
    const int ko = (lane >> 4) << 3;

    f32x4 acc[2][2] = {};

    for (int h = 0; h < 2; ++h) {
#pragma unroll
        for (int it = 0; it < 4; ++it) {
            int chunk = tid + it * 256;
            int r = chunk >> 4;
            int c = (chunk & 15) << 3;
            int ga = bi * 64 + r;
            int gb = bj * 64 + r;
            int cgl = h * 128 + c;
            const float4* pa = reinterpret_cast<const float4*>(zi) + ga * 64 + (cgl >> 2);
            const float4* pb = reinterpret_cast<const float4*>(zj) + gb * 64 + (cgl >> 2);
            float4 a0 = pa[0], a1 = pa[1];
            float4 b0 = pb[0], b1 = pb[1];
            float ia = ninv_i[ga];
            float ib = ninv_j[gb];
            short8 va, vb;
            va[0] = (short)f2bf(a0.x * ia); va[1] = (short)f2bf(a0.y * ia);
            va[2] = (short)f2bf(a0.z * ia); va[3] = (short)f2bf(a0.w * ia);
            va[4] = (short)f2bf(a1.x * ia); va[5] = (short)f2bf(a1.y * ia);
            va[6] = (short)f2bf(a1.z * ia); va[7] = (short)f2bf(a1.w * ia);
            vb[0] = (short)f2bf(b0.x * ib); vb[1] = (short)f2bf(b0.y * ib);
            vb[2] = (short)f2bf(b0.z * ib); vb[3] = (short)f2bf(b0.w * ib);
            vb[4] = (short)f2bf(b1.x * ib); vb[5] = (short)f2bf(b1.y * ib);
            vb[6] = (short)f2bf(b1.z * ib); vb[7] = (short)f2bf(b1.w * ib);
            *ldsp128(As, r, c) = va;
            *ldsp128(Bs, r, c) = vb;
        }
        __syncthreads();
#pragma unroll
        for (int kk = 0; kk < 4; ++kk) {
            int c = kk * 32 + ko;
            short8 a0 = *ldsp128(As, wr + fr, c);
            short8 a1 = *ldsp128(As, wr + 16 + fr, c);
            short8 b0 = *ldsp128(Bs, wc + fr, c);
            short8 b1 = *ldsp128(Bs, wc + 16 + fr, c);
            acc[0][0] = __builtin_amdgcn_mfma_f32_16x16x32_bf16(a0, b0, acc[0][0], 0, 0, 0);
            acc[0][1] = __builtin_amdgcn_mfma_f32_16x16x32_bf16(a0, b1, acc[0][1], 0, 0, 0);
            acc[1][0] = __builtin_amdgcn_mfma_f32_16x16x32_bf16(a1, b0, acc[1][0], 0, 0, 0);
            acc[1][1] = __builtin_amdgcn_mfma_f32_16x16x32_bf16(a1, b1, acc[1][1], 0, 0, 0);
        }
        __syncthreads();
    }

    const float SC = 2.0f * 1.44269504088896f;
    float rs[2][4];
#pragma unroll
    for (int m = 0; m < 2; ++m)
#pragma unroll
        for (int r = 0; r < 4; ++r) rs[m][r] = 0.f;
    float cs[2] = {0.f, 0.f};
#pragma unroll
    for (int m = 0; m < 2; ++m)
#pragma unroll
        for (int n = 0; n < 2; ++n)
#pragma unroll
            for (int r = 0; r < 4; ++r) {
                float e = exp2f(acc[m][n][r] * SC);
                rs[m][r] += e;
                cs[n] += e;
            }
#pragma unroll
    for (int m = 0; m < 2; ++m)
#pragma unroll
        for (int r = 0; r < 4; ++r) {
            float v = rs[m][r];
            v += __shfl_xor(v, 1); v += __shfl_xor(v, 2);
            v += __shfl_xor(v, 4); v += __shfl_xor(v, 8);
            if ((lane & 15) == 0) {
                int row = bi * 64 + wr + m * 16 + (lane >> 4) * 4 + r;
                atomicAdd(&rowsum[row], v);
            }
        }
#pragma unroll
    for (int n = 0; n < 2; ++n) {
        float v = cs[n];
        v += __shfl_xor(v, 16); v += __shfl_xor(v, 32);
        if (lane < 16) atomicAdd(&colsum[bj * 64 + wc + n * 16 + lane], v);
    }
}

__global__ __launch_bounds__(256) void loss_kernel(
    const float* __restrict__ rowsum, const float* __restrict__ colsum,
    const float* __restrict__ pos, float* __restrict__ out) {
    float a = 0.f;
    for (int i = threadIdx.x; i < BATCH; i += 256)
        a += __logf(rowsum[i]) + __logf(colsum[i]) - 4.0f * pos[i];
#pragma unroll
    for (int o = 1; o < 64; o <<= 1) a += __shfl_xor(a, o);
    __shared__ float red[4];
    if ((threadIdx.x & 63) == 0) red[threadIdx.x >> 6] = a;
    __syncthreads();
    if (threadIdx.x == 0) {
        float t = red[0] + red[1] + red[2] + red[3];
        out[0] = t * (1.0f / (2.0f * BATCH));
    }
}

extern "C" void kernel_launch(void* const* d_in, const int* in_sizes, int n_in,
                              void* d_out, int out_size, void* d_ws, size_t ws_size,
                              hipStream_t stream) {
    const float* zi = (const float*)d_in[0];
    const float* zj = (const float*)d_in[1];
    char* ws = (char*)d_ws;

    if (ws_size >= WS_FAST_BYTES) {
        unsigned short* zib = (unsigned short*)ws;
        unsigned short* zjb = (unsigned short*)(ws + (size_t)2 * 1024 * 1024);
        float* pos    = (float*)(ws + (size_t)4 * 1024 * 1024);
        float* rowsum = pos + 4096;
        float* colsum = rowsum + 4096;
        float* tmp    = colsum + 4096;
        int*   counter = (int*)(tmp + 1);
        norm2_kernel<<<BATCH / 4, 256, 0, stream>>>(zi, zj, zib, zjb, pos, rowsum, colsum, tmp, counter);
        sim2_kernel<<<512, 256, 0, stream>>>(zib, zjb, rowsum, colsum);
        loss2_kernel<<<32, 256, 0, stream>>>(rowsum, colsum, pos, tmp, counter, (float*)d_out);
    } else {
        float* wsf = (float*)ws;
        float* ninv_i = wsf;
        float* ninv_j = wsf + 4096;
        float* pos    = wsf + 8192;
        float* rowsum = wsf + 12288;
        float* colsum = wsf + 16384;
        init_kernel<<<16, 256, 0, stream>>>(rowsum, colsum);
        norm_kernel<<<BATCH / 4, 256, 0, stream>>>(zi, zj, ninv_i, ninv_j, pos);
        dim3 grid(64, 64);
        sim_kernel<<<grid, 256, 0, stream>>>(zi, zj, ninv_i, ninv_j, rowsum, colsum);
        loss_kernel<<<1, 256, 0, stream>>>(rowsum, colsum, pos, (float*)d_out);
    }
}